// Round 8
// baseline (623.368 us; speedup 1.0000x reference)
//
#include <hip/hip_runtime.h>

#define NN 50000
#define EE 100000
#define FF 64
#define HH 128
#define HEADS 4
#define BB 64
#define SS 512
#define LCC 8

// ---- bf16 helpers ----
__device__ __forceinline__ float b2f(ushort u) {
    return __uint_as_float(((unsigned)u) << 16);
}
__device__ __forceinline__ ushort f2b(float f) {
    unsigned u = __float_as_uint(f);
    unsigned r = (u + 0x7FFFu + ((u >> 16) & 1u)) >> 16;   // RNE
    return (ushort)r;
}

typedef __attribute__((ext_vector_type(4))) float f32x4;
typedef __attribute__((ext_vector_type(8))) short s16x8;

__device__ __forceinline__ void glls16(const ushort* g, ushort* l) {
    __builtin_amdgcn_global_load_lds((const __attribute__((address_space(1))) void*)g,
                                     (__attribute__((address_space(3))) void*)l, 16, 0, 0);
}

// ================= bf16 MFMA GEMM, BK=64, double-buffered LDS, XCD-swizzled grid ========
// Pipeline per K-iter: issue next tile's 8 global_load_lds into alternate LDS half,
// s_waitcnt vmcnt(8) (drain ONLY the older tile; newer 8 stay in flight across the
// barrier), s_barrier, MFMA on current half, s_barrier. Raw barriers (no vmcnt(0)
// drain). Buffer reuse distance = 2 iters; both barriers retained => safe.
// C = A[M,K] @ Bt[N,K]^T + bias; cols [0,split)->C1 (ld1), [split,N)->C2 (ld2).
// 1-D grid gx*gyp: xcd=bid&7, slot=bid>>3, bx=slot%gx, by=xcd+8*(slot/gx).
#define BM 128
#define BN 128
#define BK 64
#define TS (BM * BK)   // 8192 ushorts = 16 KB per half

__global__ __launch_bounds__(256) void gemm_bf16(
    const ushort* __restrict__ A, const ushort* __restrict__ Bt,
    const float* __restrict__ bias,
    ushort* __restrict__ C1, int ld1,
    ushort* __restrict__ C2, int ld2, int split,
    int M, int K, int relu, int gx, int gy)
{
    __shared__ __align__(16) ushort As[2 * TS];   // 32 KB
    __shared__ __align__(16) ushort Bs[2 * TS];   // 32 KB
    const int bid  = blockIdx.x;
    const int xcd  = bid & 7;
    const int slot = bid >> 3;
    const int bx   = slot % gx;
    const int by   = xcd + 8 * (slot / gx);
    if (by >= gy) return;
    const int m0 = by * BM;
    const int n0 = bx * BN;

    const int t = threadIdx.x;
    const int lane = t & 63;
    const int wave = t >> 6;
    const int wm = (wave & 1) * 64;
    const int wn = (wave >> 1) * 64;
    const int lrow = lane & 15;
    const int g    = lane >> 4;          // K-subchunk 0..3 within a 32-wide MFMA step

    // staging: issue p of wave w covers rows w*32 + p*8 + (lane>>3), chunk slot lane&7
    const int srow = (wave << 5) + (lane >> 3);
    const int scs  = lane & 7;

    // hoisted per-lane global source pointers (k0 = 0)
    const ushort* ga[4];
    const ushort* gb[4];
#pragma unroll
    for (int p = 0; p < 4; ++p) {
        const int row = srow + (p << 3);
        const int l   = scs ^ (row & 7);                    // logical chunk stored here
        ga[p] = A + (size_t)min(m0 + row, M - 1) * K + (l << 3);
        gb[p] = Bt + (size_t)(n0 + row) * K + (l << 3);
    }
    const int ldsoff = (wave << 11);

    // prologue: tile 0 -> half 0  (8 DMAs per wave)
#pragma unroll
    for (int p = 0; p < 4; ++p) glls16(ga[p], As + ldsoff + (p << 9));
#pragma unroll
    for (int p = 0; p < 4; ++p) glls16(gb[p], Bs + ldsoff + (p << 9));

    f32x4 acc[4][4] = {};
    const int nIt = K / BK;

    for (int it = 0; it < nIt; ++it) {
        const int cur = (it & 1) ? TS : 0;
        const int nxt = TS - cur;
        if (it + 1 < nIt) {
            const int ko = (it + 1) * BK;
#pragma unroll
            for (int p = 0; p < 4; ++p) glls16(ga[p] + ko, As + nxt + ldsoff + (p << 9));
#pragma unroll
            for (int p = 0; p < 4; ++p) glls16(gb[p] + ko, Bs + nxt + ldsoff + (p << 9));
            __builtin_amdgcn_s_waitcnt(0xF78);   // vmcnt(8) expcnt(7) lgkmcnt(15): older tile done
        } else {
            __builtin_amdgcn_s_waitcnt(0xF70);   // vmcnt(0): last tile done
        }
        __builtin_amdgcn_s_barrier();

#pragma unroll
        for (int kk = 0; kk < 2; ++kk) {
            s16x8 af[4], bf[4];
#pragma unroll
            for (int i = 0; i < 4; ++i) {
                const int R = wm + i * 16 + lrow;
                const int c = ((kk << 2) + g) ^ (R & 7);
                af[i] = *(const s16x8*)&As[cur + (R << 6) + (c << 3)];
            }
#pragma unroll
            for (int j = 0; j < 4; ++j) {
                const int R = wn + j * 16 + lrow;
                const int c = ((kk << 2) + g) ^ (R & 7);
                bf[j] = *(const s16x8*)&Bs[cur + (R << 6) + (c << 3)];
            }
#pragma unroll
            for (int i = 0; i < 4; ++i)
#pragma unroll
                for (int j = 0; j < 4; ++j)
                    acc[i][j] = __builtin_amdgcn_mfma_f32_16x16x32_bf16(af[i], bf[j], acc[i][j], 0, 0, 0);
        }
        __builtin_amdgcn_s_barrier();   // protect 'cur' half before it is overwritten next iter
    }

    // epilogue: row = m0+wm+i*16+(lane>>4)*4+r, col = n0+wn+j*16+(lane&15)
    const int rbase = (lane >> 4) * 4;
#pragma unroll
    for (int i = 0; i < 4; ++i) {
#pragma unroll
        for (int r = 0; r < 4; ++r) {
            const int gm = m0 + wm + i * 16 + rbase + r;
            if (gm < M) {
#pragma unroll
                for (int j = 0; j < 4; ++j) {
                    const int gcol = n0 + wn + j * 16 + lrow;
                    float v = acc[i][j][r] + bias[gcol];
                    if (relu) v = fmaxf(v, 0.f);
                    if (gcol < split) C1[(size_t)gm * ld1 + gcol] = f2b(v);
                    else              C2[(size_t)gm * ld2 + (gcol - split)] = f2b(v);
                }
            }
        }
    }
}

// ================= weight prep =================
// wt layout (rows are [n][k], bf16):
//  [0, 8192)            Wpt   [128][64]
//  [8192, 122880)       F1    [896][128]  = Ws1t(512) | head0 q|k|v (384)
//  [122880, 270336)     H1-3  3 x [384][128]
//  [270336, 532480)     F2    [512][512]  = Ws2t(128) | q2|k2|v2 (384)
// bb: [0,896) F1 bias; [896,2048) heads 1-3 bias; [2048,2560) F2 bias
#define F1OFF  8192
#define HOFF   122880
#define F2OFF  270336
#define WTOTAL 532480
#define BTOT   2560

__global__ void wprep_kernel(
    const float* __restrict__ Wp,
    const float* __restrict__ Wq1, const float* __restrict__ Wk1,
    const float* __restrict__ Wv1, const float* __restrict__ Ws1,
    const float* __restrict__ Wq2, const float* __restrict__ Wk2,
    const float* __restrict__ Wv2, const float* __restrict__ Ws2,
    const float* __restrict__ bs1,
    const float* __restrict__ bq1, const float* __restrict__ bk1, const float* __restrict__ bv1,
    const float* __restrict__ bs2,
    const float* __restrict__ bq2, const float* __restrict__ bk2, const float* __restrict__ bv2,
    ushort* __restrict__ wt, float* __restrict__ bb)
{
    int t = blockIdx.x * 256 + threadIdx.x;
    if (t < WTOTAL) {
        float v;
        if (t < F1OFF) {
            int n = t >> 6, k = t & 63;
            v = Wp[k * 128 + n];
        } else if (t < HOFF) {
            int u = t - F1OFF;
            int n = u >> 7, k = u & 127;
            if (n < 512) v = Ws1[k * 512 + n];
            else {
                int r = n - 512;
                const float* W = (r < 128) ? Wq1 : (r < 256) ? Wk1 : Wv1;
                v = W[k * 512 + (r & 127)];           // head 0
            }
        } else if (t < F2OFF) {
            int u = t - HOFF;
            int h = u / 49152 + 1;
            int w = u % 49152;
            int r = w >> 7, k = w & 127;
            const float* W = (r < 128) ? Wq1 : (r < 256) ? Wk1 : Wv1;
            v = W[k * 512 + h * 128 + (r & 127)];
        } else {
            int u = t - F2OFF;
            int n = u >> 9, k = u & 511;
            if (n < 128) v = Ws2[k * 128 + n];
            else {
                int r = n - 128;
                const float* W = (r < 128) ? Wq2 : (r < 256) ? Wk2 : Wv2;
                v = W[k * 128 + (r & 127)];
            }
        }
        wt[t] = f2b(v);
    } else if (t < WTOTAL + BTOT) {
        int u = t - WTOTAL;
        float v;
        if (u < 896) {
            v = (u < 512) ? bs1[u]
              : (u < 640) ? bq1[u - 512]
              : (u < 768) ? bk1[u - 640] : bv1[u - 768];
        } else if (u < 2048) {
            int w = u - 896;
            int h = w / 384 + 1, c = w % 384;
            const float* B = (c < 128) ? bq1 : (c < 256) ? bk1 : bv1;
            v = B[h * 128 + (c & 127)];
        } else {
            int c = u - 2048;
            v = (c < 128) ? bs2[c]
              : (c < 256) ? bq2[c - 128]
              : (c < 384) ? bk2[c - 256] : bv2[c - 384];
        }
        bb[u] = v;
    }
}

// ================= fp32 -> bf16 (x4) =================
__global__ void f32_to_bf16_kernel(const float4* __restrict__ in, ushort4* __restrict__ out, int n4)
{
    int i = blockIdx.x * 256 + threadIdx.x;
    if (i >= n4) return;
    float4 v = in[i];
    ushort4 o;
    o.x = f2b(v.x); o.y = f2b(v.y); o.z = f2b(v.z); o.w = f2b(v.w);
    out[i] = o;
}

__global__ void fill_kernel(unsigned* __restrict__ p, unsigned v, int n) {
    int i = blockIdx.x * blockDim.x + threadIdx.x;
    if (i < n) p[i] = v;
}

// ================= CSR build (dst -> sorted src list) =================
__global__ void hist_kernel(const int* __restrict__ dst, int* __restrict__ cnt, int E) {
    int e = blockIdx.x * 256 + threadIdx.x;
    if (e < E) atomicAdd(&cnt[dst[e]], 1);
}

#define SCAN_B 1024
__global__ void scan_bsum_kernel(const int* __restrict__ cnt, int* __restrict__ bsum, int n) {
    __shared__ int sd[256];
    int tid = threadIdx.x;
    int base = blockIdx.x * SCAN_B + tid * 4;
    int s = 0;
#pragma unroll
    for (int j = 0; j < 4; ++j) if (base + j < n) s += cnt[base + j];
    sd[tid] = s;
    __syncthreads();
    for (int off = 128; off > 0; off >>= 1) {
        if (tid < off) sd[tid] += sd[tid + off];
        __syncthreads();
    }
    if (tid == 0) bsum[blockIdx.x] = sd[0];
}

__global__ void scan_excl_kernel(int* __restrict__ bsum, int nb) {
    if (threadIdx.x == 0 && blockIdx.x == 0) {
        int acc = 0;
        for (int i = 0; i < nb; ++i) { int v = bsum[i]; bsum[i] = acc; acc += v; }
    }
}

// writes rowptr AND the bucket cursor (exclusive offsets)
__global__ void scan_final_kernel(const int* __restrict__ cnt, const int* __restrict__ bsum,
                                  int* __restrict__ rowptr, int* __restrict__ cursor, int n) {
    __shared__ int sd[256];
    int tid = threadIdx.x;
    int base = blockIdx.x * SCAN_B + tid * 4;
    int v[4]; int s = 0;
#pragma unroll
    for (int j = 0; j < 4; ++j) { v[j] = (base + j < n) ? cnt[base + j] : 0; s += v[j]; }
    sd[tid] = s;
    __syncthreads();
    for (int off = 1; off < 256; off <<= 1) {
        int t2 = (tid >= off) ? sd[tid - off] : 0;
        __syncthreads();
        sd[tid] += t2;
        __syncthreads();
    }
    int acc = bsum[blockIdx.x] + sd[tid] - s;
#pragma unroll
    for (int j = 0; j < 4; ++j) {
        if (base + j < n) cursor[base + j] = acc;
        acc += v[j];
        if (base + j < n) rowptr[base + j + 1] = acc;
    }
    if (blockIdx.x == 0 && tid == 0) rowptr[0] = 0;
}

__global__ void bucket_kernel(const int* __restrict__ src, const int* __restrict__ dst,
                              int* __restrict__ cursor, int* __restrict__ srcs, int E) {
    int e = blockIdx.x * 256 + threadIdx.x;
    if (e >= E) return;
    int p = atomicAdd(&cursor[dst[e]], 1);
    srcs[p] = src[e];
}

// ================= dst-centric fused attention gather =================
// One wave per dst node i:
//   out_i = skip_i + (sum_j exp(q_i.k_j * scale) * v_j) / (sum_j exp(...))
// qkv rows [q|k|v] bf16 ld 384. skip bf16, row stride lds (ushorts).
// mode 1: relu + bf16 store (stride ldo ushorts); mode 0: f32 store (stride ldo floats).
__global__ __launch_bounds__(256) void edge_gather_kernel(
    const ushort* __restrict__ qkv, const int* __restrict__ rowptr,
    const int* __restrict__ srcs, const ushort* __restrict__ skip, int lds,
    void* __restrict__ outp, int ldo, float scale, int n, int mode)
{
    int i = blockIdx.x * 4 + (threadIdx.x >> 6);
    int lane = threadIdx.x & 63;
    if (i >= n) return;
    uint sk = ((const uint*)skip)[(size_t)i * (lds >> 1) + lane];   // hoisted
    uint qv = ((const uint*)qkv)[(size_t)i * 192 + lane];
    float q0 = b2f((ushort)qv), q1 = b2f((ushort)(qv >> 16));
    int p0 = rowptr[i], p1 = rowptr[i + 1];
    float den = 0.f, o0 = 0.f, o1 = 0.f;
    int sn = (p0 < p1) ? srcs[p0] : 0;
    for (int p = p0; p < p1; ++p) {
        int s = sn;
        sn = (p + 1 < p1) ? srcs[p + 1] : 0;                        // prefetch next index
        const uint* kr = (const uint*)qkv + (size_t)s * 192 + 64;
        uint kv = kr[lane];
        uint vv = kr[lane + 64];
        float dot = q0 * b2f((ushort)kv) + q1 * b2f((ushort)(kv >> 16));
#pragma unroll
        for (int off = 32; off > 0; off >>= 1) dot += __shfl_xor(dot, off, 64);
        float ev = __expf(dot * scale);
        den += ev;
        o0 += ev * b2f((ushort)vv);
        o1 += ev * b2f((ushort)(vv >> 16));
    }
    float inv = 1.0f / (den + 1e-16f);
    float r0 = b2f((ushort)sk) + o0 * inv;
    float r1 = b2f((ushort)(sk >> 16)) + o1 * inv;
    if (mode) {
        r0 = fmaxf(r0, 0.f); r1 = fmaxf(r1, 0.f);
        ushort2 o; o.x = f2b(r0); o.y = f2b(r1);
        ((ushort2*)outp)[(size_t)i * (ldo >> 1) + lane] = o;
    } else {
        float2 o; o.x = r0; o.y = r1;
        ((float2*)outp)[(size_t)i * (ldo >> 1) + lane] = o;
    }
}

// ================= pool: run-length partial sums over sorted batch (+fused relu) =================
__global__ __launch_bounds__(256) void pool_kernel(
    const float* __restrict__ h, const int* __restrict__ batch,
    float* __restrict__ gsum, float* __restrict__ cnt, int n)
{
    int wave = threadIdx.x >> 6, lane = threadIdx.x & 63;
    int start = blockIdx.x * 256 + wave * 64;
    int end = min(start + 64, n);
    if (start >= end) return;
    int cur = batch[start];
    float a0 = 0.f, a1 = 0.f;
    int run = 0;
    for (int node = start; node < end; ++node) {
        int g = batch[node];
        if (g != cur) {
            atomicAdd(&gsum[cur * HH + lane], a0);
            atomicAdd(&gsum[cur * HH + lane + 64], a1);
            if (lane == 0) atomicAdd(&cnt[cur], (float)run);
            cur = g; a0 = a1 = 0.f; run = 0;
        }
        const float* hr = h + (size_t)node * HH;
        a0 += fmaxf(hr[lane], 0.f);
        a1 += fmaxf(hr[lane + 64], 0.f);
        ++run;
    }
    atomicAdd(&gsum[cur * HH + lane], a0);
    atomicAdd(&gsum[cur * HH + lane + 64], a1);
    if (lane == 0) atomicAdd(&cnt[cur], (float)run);
}

__global__ void pool_fin_kernel(const float* __restrict__ gsum,
                                const float* __restrict__ cnt, float* __restrict__ g)
{
    int i = blockIdx.x * blockDim.x + threadIdx.x;
    if (i < BB * HH) g[i] = gsum[i] / fmaxf(cnt[i / HH], 1.0f);
}

// ================= output heads =================
__global__ void out_heads_kernel(
    const float* __restrict__ g,
    const float* __restrict__ w0, const float* __restrict__ b0,
    const float* __restrict__ w1, const float* __restrict__ b1,
    const float* __restrict__ w2, const float* __restrict__ b2,
    const float* __restrict__ w3, const float* __restrict__ b3,
    const float* __restrict__ w4, const float* __restrict__ b4,
    const float* __restrict__ w5, const float* __restrict__ b5,
    const float* __restrict__ w6, const float* __restrict__ b6,
    float* __restrict__ out, int total)
{
    int t = blockIdx.x * blockDim.x + threadIdx.x;
    if (t >= total) return;
    const float* W; const float* bias; int cols; int local;
    if      (t < 64)    { W = w0; bias = b0; cols = 1;   local = t; }
    else if (t < 320)   { W = w1; bias = b1; cols = 4;   local = t - 64; }
    else if (t < 512)   { W = w2; bias = b2; cols = 3;   local = t - 320; }
    else if (t < 33280) { W = w3; bias = b3; cols = SS;  local = t - 512; }
    else if (t < 66048) { W = w4; bias = b4; cols = SS;  local = t - 33280; }
    else if (t < 98816) { W = w5; bias = b5; cols = SS;  local = t - 66048; }
    else                { W = w6; bias = b6; cols = LCC; local = t - 98816; }
    int b = local / cols, c = local % cols;
    const float* gr = g + b * HH;
    float acc = bias[c];
#pragma unroll 8
    for (int i = 0; i < HH; ++i) acc += gr[i] * W[i * cols + c];
    out[t] = acc;
}

// ================= orchestration =================
extern "C" void kernel_launch(void* const* d_in, const int* in_sizes, int n_in,
                              void* d_out, int out_size, void* d_ws, size_t ws_size,
                              hipStream_t stream)
{
    (void)in_sizes; (void)n_in; (void)out_size; (void)ws_size;

    const float* nf   = (const float*)d_in[0];
    const int*   ei   = (const int*)d_in[1];
    const int*   src  = ei;
    const int*   dst  = ei + EE;
    const int*   batch= (const int*)d_in[2];
    const float* Wp   = (const float*)d_in[3];
    const float* bp   = (const float*)d_in[4];
    const float* Wq1  = (const float*)d_in[5];
    const float* bq1  = (const float*)d_in[6];
    const float* Wk1  = (const float*)d_in[7];
    const float* bk1  = (const float*)d_in[8];
    const float* Wv1  = (const float*)d_in[9];
    const float* bv1  = (const float*)d_in[10];
    const float* Ws1  = (const float*)d_in[11];
    const float* bs1  = (const float*)d_in[12];
    const float* Wq2  = (const float*)d_in[13];
    const float* bq2  = (const float*)d_in[14];
    const float* Wk2  = (const float*)d_in[15];
    const float* bk2  = (const float*)d_in[16];
    const float* Wv2  = (const float*)d_in[17];
    const float* bv2  = (const float*)d_in[18];
    const float* Ws2  = (const float*)d_in[19];
    const float* bs2  = (const float*)d_in[20];
    const float* crW  = (const float*)d_in[21];
    const float* crb  = (const float*)d_in[22];
    const float* hlW  = (const float*)d_in[23];
    const float* hlb  = (const float*)d_in[24];
    const float* mtW  = (const float*)d_in[25];
    const float* mtb  = (const float*)d_in[26];
    const float* p1W  = (const float*)d_in[27];
    const float* p1b  = (const float*)d_in[28];
    const float* p2W  = (const float*)d_in[29];
    const float* p2b  = (const float*)d_in[30];
    const float* dtW  = (const float*)d_in[31];
    const float* dtb  = (const float*)d_in[32];
    const float* slW  = (const float*)d_in[33];
    const float* slb  = (const float*)d_in[34];
    float* out = (float*)d_out;

    // ---- workspace layout (~194 MB, under the proven 232.3 MB) ----
    float*  h2     = (float*)d_ws;                         // N*128 f32 (conv2 result for pool)
    ushort* nfb    = (ushort*)h2;                          // N*64 bf16 (aliases h2; consumed before h2 written)
    ushort* h0b    = (ushort*)(h2 + (size_t)NN * 128);     // N*128 bf16
    ushort* skipb  = h0b + (size_t)NN * 128;               // N*512 bf16 (conv1 skip)
    ushort* h1b    = skipb + (size_t)NN * 512;             // N*512 bf16 (conv1 out)
    ushort* h2sb   = h1b + (size_t)NN * 512;               // N*128 bf16 (conv2 skip)
    ushort* qkvb   = h2sb + (size_t)NN * 128;              // N*384 bf16 (q|k|v, reused)
    ushort* wt     = qkvb + (size_t)NN * 384;              // prepped weights
    float*  bb     = (float*)(wt + WTOTAL);                // fused biases
    int*    rowptr = (int*)(bb + BTOT);                    // N+1
    int*    srcs   = rowptr + NN + 1;                      // E
    int*    cnt    = srcs + EE;                            // N (hist)
    int*    cursor = cnt + NN;                             // N
    int*    bsum   = cursor + NN;                          // 64
    float*  gsum   = (float*)(bsum + 64);                  // B*128
    float*  cntb   = gsum + BB * HH;                       // B
    float*  gbuf   = cntb + BB;                            // B*128

    const float scale = 0.08838834764831845f; // 1/sqrt(128)
    const dim3 blk(256);
    const int gy  = (NN + BM - 1) / BM;         // 391 row-blocks
    const int gyp = ((gy + 7) / 8) * 8;         // 392 (XCD-padded)
    const int nb = (NN + SCAN_B - 1) / SCAN_B;  // 49

    // 1) weight prep
    wprep_kernel<<<(WTOTAL + BTOT + 255) / 256, blk, 0, stream>>>(
        Wp, Wq1, Wk1, Wv1, Ws1, Wq2, Wk2, Wv2, Ws2,
        bs1, bq1, bk1, bv1, bs2, bq2, bk2, bv2, wt, bb);

    // 2) nf -> bf16
    f32_to_bf16_kernel<<<((NN * FF / 4) + 255) / 256, blk, 0, stream>>>(
        (const float4*)nf, (ushort4*)nfb, NN * FF / 4);

    // 3) CSR build
    fill_kernel<<<(NN + 255) / 256, blk, 0, stream>>>((unsigned*)cnt, 0u, NN);
    hist_kernel<<<(EE + 255) / 256, blk, 0, stream>>>(dst, cnt, EE);
    scan_bsum_kernel<<<nb, blk, 0, stream>>>(cnt, bsum, NN);
    scan_excl_kernel<<<1, 64, 0, stream>>>(bsum, nb);
    scan_final_kernel<<<nb, blk, 0, stream>>>(cnt, bsum, rowptr, cursor, NN);
    bucket_kernel<<<(EE + 255) / 256, blk, 0, stream>>>(src, dst, cursor, srcs, EE);

    // 4) h0b = relu(nf @ Wp + bp)     (gx=1)
    gemm_bf16<<<dim3(1 * gyp), blk, 0, stream>>>(
        nfb, wt, bp, h0b, HH, h0b, HH, HH, NN, FF, 1, 1, gy);

    // 5) F1: skip1 (cols 0..511 -> skipb) + head0 qkv (cols 512..895 -> qkvb)  (gx=7)
    gemm_bf16<<<dim3(7 * gyp), blk, 0, stream>>>(
        h0b, wt + F1OFF, bb, skipb, 512, qkvb, 384, 512, NN, HH, 0, 7, gy);
    edge_gather_kernel<<<(NN + 3) / 4, blk, 0, stream>>>(
        qkvb, rowptr, srcs, skipb + 0 * HH, 512, (void*)(h1b + 0 * HH), 512, scale, NN, 1);

    // 6) conv1 heads 1..3  (gx=3)
    for (int h = 1; h < HEADS; ++h) {
        gemm_bf16<<<dim3(3 * gyp), blk, 0, stream>>>(
            h0b, wt + HOFF + (h - 1) * 49152, bb + 896 + (h - 1) * 384,
            qkvb, 384, qkvb, 384, 384, NN, HH, 0, 3, gy);
        edge_gather_kernel<<<(NN + 3) / 4, blk, 0, stream>>>(
            qkvb, rowptr, srcs, skipb + h * HH, 512, (void*)(h1b + h * HH), 512, scale, NN, 1);
    }

    // 7) F2: conv2 skip (cols 0..127 -> h2sb) + qkv (cols 128..511 -> qkvb)  (gx=4)
    gemm_bf16<<<dim3(4 * gyp), blk, 0, stream>>>(
        h1b, wt + F2OFF, bb + 2048, h2sb, 128, qkvb, 384, 128, NN, 4 * HH, 0, 4, gy);
    edge_gather_kernel<<<(NN + 3) / 4, blk, 0, stream>>>(
        qkvb, rowptr, srcs, h2sb, 128, (void*)h2, 128, scale, NN, 0);

    // 8) pool (relu fused)
    fill_kernel<<<(BB * HH + BB + 255) / 256, blk, 0, stream>>>((unsigned*)gsum, 0u, BB * HH + BB);
    pool_kernel<<<(NN + 255) / 256, blk, 0, stream>>>(h2, batch, gsum, cntb, NN);
    pool_fin_kernel<<<(BB * HH + 255) / 256, blk, 0, stream>>>(gsum, cntb, gbuf);

    // 9) output heads
    const int total = BB * (1 + 4 + 3 + SS + SS + SS + LCC);
    out_heads_kernel<<<(total + 255) / 256, blk, 0, stream>>>(
        gbuf, crW, crb, hlW, hlb, mtW, mtb, p1W, p1b, p2W, p2b, dtW, dtb, slW, slb, out, total);
}

// Round 9
// 545.806 us; speedup vs baseline: 1.1421x; 1.1421x over previous
//
#include <hip/hip_runtime.h>

#define NN 50000
#define EE 100000
#define FF 64
#define HH 128
#define HEADS 4
#define BB 64
#define SS 512
#define LCC 8

// ---- bf16 helpers ----
__device__ __forceinline__ float b2f(ushort u) {
    return __uint_as_float(((unsigned)u) << 16);
}
__device__ __forceinline__ ushort f2b(float f) {
    unsigned u = __float_as_uint(f);
    unsigned r = (u + 0x7FFFu + ((u >> 16) & 1u)) >> 16;   // RNE
    return (ushort)r;
}

typedef __attribute__((ext_vector_type(4))) float f32x4;
typedef __attribute__((ext_vector_type(8))) short s16x8;

__device__ __forceinline__ void glls16(const ushort* g, ushort* l) {
    __builtin_amdgcn_global_load_lds((const __attribute__((address_space(1))) void*)g,
                                     (__attribute__((address_space(3))) void*)l, 16, 0, 0);
}

// ================= bf16 MFMA GEMM, BK=32 double-buffered, XCD-swizzled grid ========
// LDS stays 32 KB total (2 x 8 KB per operand) -> 4 blocks/CU (round-7 occupancy)
// PLUS cross-tile prefetch: issue next tile into alternate half, s_waitcnt vmcnt(4)
// (drains only the older tile; the newer 4 DMAs stay in flight across the barrier),
// raw s_barrier (no vmcnt(0) drain), compute, barrier. Buffer reuse distance 2 iters.
// Swizzle: 16-B chunks XOR'd by ((row>>1)&3) — 0 conflicts (measured r5-r7).
// C = A[M,K] @ Bt[N,K]^T + bias; cols [0,split)->C1 (ld1), [split,N)->C2 (ld2).
// 1-D grid gx*gyp: xcd=bid&7, slot=bid>>3, bx=slot%gx, by=xcd+8*(slot/gx).
#define BM 128
#define BN 128
#define BK 32
#define TS (BM * BK)   // 4096 ushorts = 8 KB per half

__global__ __launch_bounds__(256) void gemm_bf16(
    const ushort* __restrict__ A, const ushort* __restrict__ Bt,
    const float* __restrict__ bias,
    ushort* __restrict__ C1, int ld1,
    ushort* __restrict__ C2, int ld2, int split,
    int M, int K, int relu, int gx, int gy)
{
    __shared__ __align__(16) ushort As[2 * TS];   // 16 KB
    __shared__ __align__(16) ushort Bs[2 * TS];   // 16 KB
    const int bid  = blockIdx.x;
    const int xcd  = bid & 7;
    const int slot = bid >> 3;
    const int bx   = slot % gx;
    const int by   = xcd + 8 * (slot / gx);
    if (by >= gy) return;
    const int m0 = by * BM;
    const int n0 = bx * BN;

    const int t = threadIdx.x;
    const int lane = t & 63;
    const int wave = t >> 6;
    const int wm = (wave & 1) * 64;
    const int wn = (wave >> 1) * 64;
    const int lrow = lane & 15;
    const int g    = lane >> 4;          // logical k-chunk 0..3 (8 bf16 each)

    // staging: wave covers tile rows [wave*32, wave*32+32), 2 issues of 16 rows
    const int r0 = (wave << 5) + (lane >> 2);
    const int c0 = lane & 3;

    // hoisted per-lane global source pointers (k0 = 0)
    const ushort* ga[2];
    const ushort* gb[2];
#pragma unroll
    for (int p = 0; p < 2; ++p) {
        const int row = r0 + (p << 4);
        const int lc  = c0 ^ ((row >> 1) & 3);
        ga[p] = A + (size_t)min(m0 + row, M - 1) * K + (lc << 3);
        gb[p] = Bt + (size_t)(n0 + row) * K + (lc << 3);
    }
    const int ldsoff = (wave << 10);

    // prologue: tile 0 -> half 0 (4 DMAs per wave)
#pragma unroll
    for (int p = 0; p < 2; ++p) glls16(ga[p], As + ldsoff + (p << 9));
#pragma unroll
    for (int p = 0; p < 2; ++p) glls16(gb[p], Bs + ldsoff + (p << 9));

    f32x4 acc[4][4] = {};
    const int nIt = K / BK;

    for (int it = 0; it < nIt; ++it) {
        const int cur = (it & 1) ? TS : 0;
        const int nxt = TS - cur;
        if (it + 1 < nIt) {
            const int ko = (it + 1) * BK;
#pragma unroll
            for (int p = 0; p < 2; ++p) glls16(ga[p] + ko, As + nxt + ldsoff + (p << 9));
#pragma unroll
            for (int p = 0; p < 2; ++p) glls16(gb[p] + ko, Bs + nxt + ldsoff + (p << 9));
            asm volatile("s_waitcnt vmcnt(4)" ::: "memory");   // older tile done; newer 4 in flight
        } else {
            asm volatile("s_waitcnt vmcnt(0)" ::: "memory");   // last tile done
        }
        asm volatile("s_barrier" ::: "memory");

        s16x8 af[4], bf[4];
#pragma unroll
        for (int i = 0; i < 4; ++i) {
            const int R = wm + i * 16 + lrow;
            const int sc = g ^ ((R >> 1) & 3);
            af[i] = *(const s16x8*)&As[cur + (R << 5) + (sc << 3)];
        }
#pragma unroll
        for (int j = 0; j < 4; ++j) {
            const int R = wn + j * 16 + lrow;
            const int sc = g ^ ((R >> 1) & 3);
            bf[j] = *(const s16x8*)&Bs[cur + (R << 5) + (sc << 3)];
        }
#pragma unroll
        for (int i = 0; i < 4; ++i)
#pragma unroll
            for (int j = 0; j < 4; ++j)
                acc[i][j] = __builtin_amdgcn_mfma_f32_16x16x32_bf16(af[i], bf[j], acc[i][j], 0, 0, 0);
        asm volatile("s_barrier" ::: "memory");   // protect 'cur' before overwrite next iter
    }

    // epilogue: row = m0+wm+i*16+(lane>>4)*4+r, col = n0+wn+j*16+(lane&15)
    const int rbase = (lane >> 4) * 4;
#pragma unroll
    for (int i = 0; i < 4; ++i) {
#pragma unroll
        for (int r = 0; r < 4; ++r) {
            const int gm = m0 + wm + i * 16 + rbase + r;
            if (gm < M) {
#pragma unroll
                for (int j = 0; j < 4; ++j) {
                    const int gcol = n0 + wn + j * 16 + lrow;
                    float v = acc[i][j][r] + bias[gcol];
                    if (relu) v = fmaxf(v, 0.f);
                    if (gcol < split) C1[(size_t)gm * ld1 + gcol] = f2b(v);
                    else              C2[(size_t)gm * ld2 + (gcol - split)] = f2b(v);
                }
            }
        }
    }
}

// ================= weight prep =================
// wt layout (rows are [n][k], bf16):
//  [0, 8192)            Wpt   [128][64]
//  [8192, 122880)       F1    [896][128]  = Ws1t(512) | head0 q|k|v (384)
//  [122880, 270336)     H1-3  3 x [384][128]
//  [270336, 532480)     F2    [512][512]  = Ws2t(128) | q2|k2|v2 (384)
// bb: [0,896) F1 bias; [896,2048) heads 1-3 bias; [2048,2560) F2 bias
#define F1OFF  8192
#define HOFF   122880
#define F2OFF  270336
#define WTOTAL 532480
#define BTOT   2560

__global__ void wprep_kernel(
    const float* __restrict__ Wp,
    const float* __restrict__ Wq1, const float* __restrict__ Wk1,
    const float* __restrict__ Wv1, const float* __restrict__ Ws1,
    const float* __restrict__ Wq2, const float* __restrict__ Wk2,
    const float* __restrict__ Wv2, const float* __restrict__ Ws2,
    const float* __restrict__ bs1,
    const float* __restrict__ bq1, const float* __restrict__ bk1, const float* __restrict__ bv1,
    const float* __restrict__ bs2,
    const float* __restrict__ bq2, const float* __restrict__ bk2, const float* __restrict__ bv2,
    ushort* __restrict__ wt, float* __restrict__ bb)
{
    int t = blockIdx.x * 256 + threadIdx.x;
    if (t < WTOTAL) {
        float v;
        if (t < F1OFF) {
            int n = t >> 6, k = t & 63;
            v = Wp[k * 128 + n];
        } else if (t < HOFF) {
            int u = t - F1OFF;
            int n = u >> 7, k = u & 127;
            if (n < 512) v = Ws1[k * 512 + n];
            else {
                int r = n - 512;
                const float* W = (r < 128) ? Wq1 : (r < 256) ? Wk1 : Wv1;
                v = W[k * 512 + (r & 127)];           // head 0
            }
        } else if (t < F2OFF) {
            int u = t - HOFF;
            int h = u / 49152 + 1;
            int w = u % 49152;
            int r = w >> 7, k = w & 127;
            const float* W = (r < 128) ? Wq1 : (r < 256) ? Wk1 : Wv1;
            v = W[k * 512 + h * 128 + (r & 127)];
        } else {
            int u = t - F2OFF;
            int n = u >> 9, k = u & 511;
            if (n < 128) v = Ws2[k * 128 + n];
            else {
                int r = n - 128;
                const float* W = (r < 128) ? Wq2 : (r < 256) ? Wk2 : Wv2;
                v = W[k * 128 + (r & 127)];
            }
        }
        wt[t] = f2b(v);
    } else if (t < WTOTAL + BTOT) {
        int u = t - WTOTAL;
        float v;
        if (u < 896) {
            v = (u < 512) ? bs1[u]
              : (u < 640) ? bq1[u - 512]
              : (u < 768) ? bk1[u - 640] : bv1[u - 768];
        } else if (u < 2048) {
            int w = u - 896;
            int h = w / 384 + 1, c = w % 384;
            const float* B = (c < 128) ? bq1 : (c < 256) ? bk1 : bv1;
            v = B[h * 128 + (c & 127)];
        } else {
            int c = u - 2048;
            v = (c < 128) ? bs2[c]
              : (c < 256) ? bq2[c - 128]
              : (c < 384) ? bk2[c - 256] : bv2[c - 384];
        }
        bb[u] = v;
    }
}

// ================= fp32 -> bf16 (x4) =================
__global__ void f32_to_bf16_kernel(const float4* __restrict__ in, ushort4* __restrict__ out, int n4)
{
    int i = blockIdx.x * 256 + threadIdx.x;
    if (i >= n4) return;
    float4 v = in[i];
    ushort4 o;
    o.x = f2b(v.x); o.y = f2b(v.y); o.z = f2b(v.z); o.w = f2b(v.w);
    out[i] = o;
}

__global__ void fill_kernel(unsigned* __restrict__ p, unsigned v, int n) {
    int i = blockIdx.x * blockDim.x + threadIdx.x;
    if (i < n) p[i] = v;
}

// ================= CSR build (dst -> sorted src list) =================
__global__ void hist_kernel(const int* __restrict__ dst, int* __restrict__ cnt, int E) {
    int e = blockIdx.x * 256 + threadIdx.x;
    if (e < E) atomicAdd(&cnt[dst[e]], 1);
}

#define SCAN_B 1024
__global__ void scan_bsum_kernel(const int* __restrict__ cnt, int* __restrict__ bsum, int n) {
    __shared__ int sd[256];
    int tid = threadIdx.x;
    int base = blockIdx.x * SCAN_B + tid * 4;
    int s = 0;
#pragma unroll
    for (int j = 0; j < 4; ++j) if (base + j < n) s += cnt[base + j];
    sd[tid] = s;
    __syncthreads();
    for (int off = 128; off > 0; off >>= 1) {
        if (tid < off) sd[tid] += sd[tid + off];
        __syncthreads();
    }
    if (tid == 0) bsum[blockIdx.x] = sd[0];
}

__global__ void scan_excl_kernel(int* __restrict__ bsum, int nb) {
    if (threadIdx.x == 0 && blockIdx.x == 0) {
        int acc = 0;
        for (int i = 0; i < nb; ++i) { int v = bsum[i]; bsum[i] = acc; acc += v; }
    }
}

// writes rowptr AND the bucket cursor (exclusive offsets)
__global__ void scan_final_kernel(const int* __restrict__ cnt, const int* __restrict__ bsum,
                                  int* __restrict__ rowptr, int* __restrict__ cursor, int n) {
    __shared__ int sd[256];
    int tid = threadIdx.x;
    int base = blockIdx.x * SCAN_B + tid * 4;
    int v[4]; int s = 0;
#pragma unroll
    for (int j = 0; j < 4; ++j) { v[j] = (base + j < n) ? cnt[base + j] : 0; s += v[j]; }
    sd[tid] = s;
    __syncthreads();
    for (int off = 1; off < 256; off <<= 1) {
        int t2 = (tid >= off) ? sd[tid - off] : 0;
        __syncthreads();
        sd[tid] += t2;
        __syncthreads();
    }
    int acc = bsum[blockIdx.x] + sd[tid] - s;
#pragma unroll
    for (int j = 0; j < 4; ++j) {
        if (base + j < n) cursor[base + j] = acc;
        acc += v[j];
        if (base + j < n) rowptr[base + j + 1] = acc;
    }
    if (blockIdx.x == 0 && tid == 0) rowptr[0] = 0;
}

__global__ void bucket_kernel(const int* __restrict__ src, const int* __restrict__ dst,
                              int* __restrict__ cursor, int* __restrict__ srcs, int E) {
    int e = blockIdx.x * 256 + threadIdx.x;
    if (e >= E) return;
    int p = atomicAdd(&cursor[dst[e]], 1);
    srcs[p] = src[e];
}

// ================= dst-centric fused attention gather (ILP-2 over edges) =================
// One wave per dst node i:
//   out_i = skip_i + (sum_j exp(q_i.k_j * scale) * v_j) / (sum_j exp(...))
// qkv rows [q|k|v] bf16 ld 384. skip bf16, row stride lds (ushorts).
// mode 1: relu + bf16 store (stride ldo ushorts); mode 0: f32 store (stride ldo floats).
__global__ __launch_bounds__(256) void edge_gather_kernel(
    const ushort* __restrict__ qkv, const int* __restrict__ rowptr,
    const int* __restrict__ srcs, const ushort* __restrict__ skip, int lds,
    void* __restrict__ outp, int ldo, float scale, int n, int mode)
{
    int i = blockIdx.x * 4 + (threadIdx.x >> 6);
    int lane = threadIdx.x & 63;
    if (i >= n) return;
    uint sk = ((const uint*)skip)[(size_t)i * (lds >> 1) + lane];   // hoisted
    uint qv = ((const uint*)qkv)[(size_t)i * 192 + lane];
    float q0 = b2f((ushort)qv), q1 = b2f((ushort)(qv >> 16));
    int p0 = rowptr[i], p1 = rowptr[i + 1];
    float den = 0.f, o0 = 0.f, o1 = 0.f;
    int p = p0;
    for (; p + 2 <= p1; p += 2) {                 // two edges in flight
        int s0 = srcs[p], s1 = srcs[p + 1];
        const uint* kr0 = (const uint*)qkv + (size_t)s0 * 192 + 64;
        const uint* kr1 = (const uint*)qkv + (size_t)s1 * 192 + 64;
        uint kv0 = kr0[lane], vv0 = kr0[lane + 64];
        uint kv1 = kr1[lane], vv1 = kr1[lane + 64];
        float d0 = q0 * b2f((ushort)kv0) + q1 * b2f((ushort)(kv0 >> 16));
        float d1 = q0 * b2f((ushort)kv1) + q1 * b2f((ushort)(kv1 >> 16));
#pragma unroll
        for (int off = 32; off > 0; off >>= 1) {
            d0 += __shfl_xor(d0, off, 64);
            d1 += __shfl_xor(d1, off, 64);
        }
        float e0 = __expf(d0 * scale), e1 = __expf(d1 * scale);
        den += e0 + e1;
        o0 += e0 * b2f((ushort)vv0) + e1 * b2f((ushort)vv1);
        o1 += e0 * b2f((ushort)(vv0 >> 16)) + e1 * b2f((ushort)(vv1 >> 16));
    }
    if (p < p1) {                                 // tail edge
        int s = srcs[p];
        const uint* kr = (const uint*)qkv + (size_t)s * 192 + 64;
        uint kv = kr[lane], vv = kr[lane + 64];
        float d = q0 * b2f((ushort)kv) + q1 * b2f((ushort)(kv >> 16));
#pragma unroll
        for (int off = 32; off > 0; off >>= 1) d += __shfl_xor(d, off, 64);
        float e = __expf(d * scale);
        den += e;
        o0 += e * b2f((ushort)vv);
        o1 += e * b2f((ushort)(vv >> 16));
    }
    float inv = 1.0f / (den + 1e-16f);
    float r0 = b2f((ushort)sk) + o0 * inv;
    float r1 = b2f((ushort)(sk >> 16)) + o1 * inv;
    if (mode) {
        r0 = fmaxf(r0, 0.f); r1 = fmaxf(r1, 0.f);
        ushort2 o; o.x = f2b(r0); o.y = f2b(r1);
        ((ushort2*)outp)[(size_t)i * (ldo >> 1) + lane] = o;
    } else {
        float2 o; o.x = r0; o.y = r1;
        ((float2*)outp)[(size_t)i * (ldo >> 1) + lane] = o;
    }
}

// ================= pool: run-length partial sums over sorted batch (+fused relu) =================
__global__ __launch_bounds__(256) void pool_kernel(
    const float* __restrict__ h, const int* __restrict__ batch,
    float* __restrict__ gsum, float* __restrict__ cnt, int n)
{
    int wave = threadIdx.x >> 6, lane = threadIdx.x & 63;
    int start = blockIdx.x * 256 + wave * 64;
    int end = min(start + 64, n);
    if (start >= end) return;
    int cur = batch[start];
    float a0 = 0.f, a1 = 0.f;
    int run = 0;
    for (int node = start; node < end; ++node) {
        int g = batch[node];
        if (g != cur) {
            atomicAdd(&gsum[cur * HH + lane], a0);
            atomicAdd(&gsum[cur * HH + lane + 64], a1);
            if (lane == 0) atomicAdd(&cnt[cur], (float)run);
            cur = g; a0 = a1 = 0.f; run = 0;
        }
        const float* hr = h + (size_t)node * HH;
        a0 += fmaxf(hr[lane], 0.f);
        a1 += fmaxf(hr[lane + 64], 0.f);
        ++run;
    }
    atomicAdd(&gsum[cur * HH + lane], a0);
    atomicAdd(&gsum[cur * HH + lane + 64], a1);
    if (lane == 0) atomicAdd(&cnt[cur], (float)run);
}

__global__ void pool_fin_kernel(const float* __restrict__ gsum,
                                const float* __restrict__ cnt, float* __restrict__ g)
{
    int i = blockIdx.x * blockDim.x + threadIdx.x;
    if (i < BB * HH) g[i] = gsum[i] / fmaxf(cnt[i / HH], 1.0f);
}

// ================= output heads =================
__global__ void out_heads_kernel(
    const float* __restrict__ g,
    const float* __restrict__ w0, const float* __restrict__ b0,
    const float* __restrict__ w1, const float* __restrict__ b1,
    const float* __restrict__ w2, const float* __restrict__ b2,
    const float* __restrict__ w3, const float* __restrict__ b3,
    const float* __restrict__ w4, const float* __restrict__ b4,
    const float* __restrict__ w5, const float* __restrict__ b5,
    const float* __restrict__ w6, const float* __restrict__ b6,
    float* __restrict__ out, int total)
{
    int t = blockIdx.x * blockDim.x + threadIdx.x;
    if (t >= total) return;
    const float* W; const float* bias; int cols; int local;
    if      (t < 64)    { W = w0; bias = b0; cols = 1;   local = t; }
    else if (t < 320)   { W = w1; bias = b1; cols = 4;   local = t - 64; }
    else if (t < 512)   { W = w2; bias = b2; cols = 3;   local = t - 320; }
    else if (t < 33280) { W = w3; bias = b3; cols = SS;  local = t - 512; }
    else if (t < 66048) { W = w4; bias = b4; cols = SS;  local = t - 33280; }
    else if (t < 98816) { W = w5; bias = b5; cols = SS;  local = t - 66048; }
    else                { W = w6; bias = b6; cols = LCC; local = t - 98816; }
    int b = local / cols, c = local % cols;
    const float* gr = g + b * HH;
    float acc = bias[c];
#pragma unroll 8
    for (int i = 0; i < HH; ++i) acc += gr[i] * W[i * cols + c];
    out[t] = acc;
}

// ================= orchestration =================
extern "C" void kernel_launch(void* const* d_in, const int* in_sizes, int n_in,
                              void* d_out, int out_size, void* d_ws, size_t ws_size,
                              hipStream_t stream)
{
    (void)in_sizes; (void)n_in; (void)out_size; (void)ws_size;

    const float* nf   = (const float*)d_in[0];
    const int*   ei   = (const int*)d_in[1];
    const int*   src  = ei;
    const int*   dst  = ei + EE;
    const int*   batch= (const int*)d_in[2];
    const float* Wp   = (const float*)d_in[3];
    const float* bp   = (const float*)d_in[4];
    const float* Wq1  = (const float*)d_in[5];
    const float* bq1  = (const float*)d_in[6];
    const float* Wk1  = (const float*)d_in[7];
    const float* bk1  = (const float*)d_in[8];
    const float* Wv1  = (const float*)d_in[9];
    const float* bv1  = (const float*)d_in[10];
    const float* Ws1  = (const float*)d_in[11];
    const float* bs1  = (const float*)d_in[12];
    const float* Wq2  = (const float*)d_in[13];
    const float* bq2  = (const float*)d_in[14];
    const float* Wk2  = (const float*)d_in[15];
    const float* bk2  = (const float*)d_in[16];
    const float* Wv2  = (const float*)d_in[17];
    const float* bv2  = (const float*)d_in[18];
    const float* Ws2  = (const float*)d_in[19];
    const float* bs2  = (const float*)d_in[20];
    const float* crW  = (const float*)d_in[21];
    const float* crb  = (const float*)d_in[22];
    const float* hlW  = (const float*)d_in[23];
    const float* hlb  = (const float*)d_in[24];
    const float* mtW  = (const float*)d_in[25];
    const float* mtb  = (const float*)d_in[26];
    const float* p1W  = (const float*)d_in[27];
    const float* p1b  = (const float*)d_in[28];
    const float* p2W  = (const float*)d_in[29];
    const float* p2b  = (const float*)d_in[30];
    const float* dtW  = (const float*)d_in[31];
    const float* dtb  = (const float*)d_in[32];
    const float* slW  = (const float*)d_in[33];
    const float* slb  = (const float*)d_in[34];
    float* out = (float*)d_out;

    // ---- workspace layout (~194 MB, under the proven 232.3 MB) ----
    float*  h2     = (float*)d_ws;                         // N*128 f32 (conv2 result for pool)
    ushort* nfb    = (ushort*)h2;                          // N*64 bf16 (aliases h2; consumed before h2 written)
    ushort* h0b    = (ushort*)(h2 + (size_t)NN * 128);     // N*128 bf16
    ushort* skipb  = h0b + (size_t)NN * 128;               // N*512 bf16 (conv1 skip)
    ushort* h1b    = skipb + (size_t)NN * 512;             // N*512 bf16 (conv1 out)
    ushort* h2sb   = h1b + (size_t)NN * 512;               // N*128 bf16 (conv2 skip)
    ushort* qkvb   = h2sb + (size_t)NN * 128;              // N*384 bf16 (q|k|v, reused)
    ushort* wt     = qkvb + (size_t)NN * 384;              // prepped weights
    float*  bb     = (float*)(wt + WTOTAL);                // fused biases
    int*    rowptr = (int*)(bb + BTOT);                    // N+1
    int*    srcs   = rowptr + NN + 1;                      // E
    int*    cnt    = srcs + EE;                            // N (hist)
    int*    cursor = cnt + NN;                             // N
    int*    bsum   = cursor + NN;                          // 64
    float*  gsum   = (float*)(bsum + 64);                  // B*128
    float*  cntb   = gsum + BB * HH;                       // B
    float*  gbuf   = cntb + BB;                            // B*128

    const float scale = 0.08838834764831845f; // 1/sqrt(128)
    const dim3 blk(256);
    const int gy  = (NN + BM - 1) / BM;         // 391 row-blocks
    const int gyp = ((gy + 7) / 8) * 8;         // 392 (XCD-padded)
    const int nb = (NN + SCAN_B - 1) / SCAN_B;  // 49

    // 1) weight prep
    wprep_kernel<<<(WTOTAL + BTOT + 255) / 256, blk, 0, stream>>>(
        Wp, Wq1, Wk1, Wv1, Ws1, Wq2, Wk2, Wv2, Ws2,
        bs1, bq1, bk1, bv1, bs2, bq2, bk2, bv2, wt, bb);

    // 2) nf -> bf16
    f32_to_bf16_kernel<<<((NN * FF / 4) + 255) / 256, blk, 0, stream>>>(
        (const float4*)nf, (ushort4*)nfb, NN * FF / 4);

    // 3) CSR build
    fill_kernel<<<(NN + 255) / 256, blk, 0, stream>>>((unsigned*)cnt, 0u, NN);
    hist_kernel<<<(EE + 255) / 256, blk, 0, stream>>>(dst, cnt, EE);
    scan_bsum_kernel<<<nb, blk, 0, stream>>>(cnt, bsum, NN);
    scan_excl_kernel<<<1, 64, 0, stream>>>(bsum, nb);
    scan_final_kernel<<<nb, blk, 0, stream>>>(cnt, bsum, rowptr, cursor, NN);
    bucket_kernel<<<(EE + 255) / 256, blk, 0, stream>>>(src, dst, cursor, srcs, EE);

    // 4) h0b = relu(nf @ Wp + bp)     (gx=1)
    gemm_bf16<<<dim3(1 * gyp), blk, 0, stream>>>(
        nfb, wt, bp, h0b, HH, h0b, HH, HH, NN, FF, 1, 1, gy);

    // 5) F1: skip1 (cols 0..511 -> skipb) + head0 qkv (cols 512..895 -> qkvb)  (gx=7)
    gemm_bf16<<<dim3(7 * gyp), blk, 0, stream>>>(
        h0b, wt + F1OFF, bb, skipb, 512, qkvb, 384, 512, NN, HH, 0, 7, gy);
    edge_gather_kernel<<<(NN + 3) / 4, blk, 0, stream>>>(
        qkvb, rowptr, srcs, skipb + 0 * HH, 512, (void*)(h1b + 0 * HH), 512, scale, NN, 1);

    // 6) conv1 heads 1..3  (gx=3)
    for (int h = 1; h < HEADS; ++h) {
        gemm_bf16<<<dim3(3 * gyp), blk, 0, stream>>>(
            h0b, wt + HOFF + (h - 1) * 49152, bb + 896 + (h - 1) * 384,
            qkvb, 384, qkvb, 384, 384, NN, HH, 0, 3, gy);
        edge_gather_kernel<<<(NN + 3) / 4, blk, 0, stream>>>(
            qkvb, rowptr, srcs, skipb + h * HH, 512, (void*)(h1b + h * HH), 512, scale, NN, 1);
    }

    // 7) F2: conv2 skip (cols 0..127 -> h2sb) + qkv (cols 128..511 -> qkvb)  (gx=4)
    gemm_bf16<<<dim3(4 * gyp), blk, 0, stream>>>(
        h1b, wt + F2OFF, bb + 2048, h2sb, 128, qkvb, 384, 128, NN, 4 * HH, 0, 4, gy);
    edge_gather_kernel<<<(NN + 3) / 4, blk, 0, stream>>>(
        qkvb, rowptr, srcs, h2sb, 128, (void*)h2, 128, scale, NN, 0);

    // 8) pool (relu fused)
    fill_kernel<<<(BB * HH + BB + 255) / 256, blk, 0, stream>>>((unsigned*)gsum, 0u, BB * HH + BB);
    pool_kernel<<<(NN + 255) / 256, blk, 0, stream>>>(h2, batch, gsum, cntb, NN);
    pool_fin_kernel<<<(BB * HH + 255) / 256, blk, 0, stream>>>(gsum, cntb, gbuf);

    // 9) output heads
    const int total = BB * (1 + 4 + 3 + SS + SS + SS + LCC);
    out_heads_kernel<<<(total + 255) / 256, blk, 0, stream>>>(
        gbuf, crW, crb, hlW, hlb, mtW, mtb, p1W, p1b, p2W, p2b, dtW, dtb, slW, slb, out, total);
}